// Round 16
// baseline (260.071 us; speedup 1.0000x reference)
//
#include <hip/hip_runtime.h>
#include <hip/hip_cooperative_groups.h>
#include <stdint.h>

namespace cg = cooperative_groups;

#define M_NODES 2048
#define KSEL 16
#define BATCH 16

typedef unsigned int u32;

// compare-exchange ascending (explicit min/max -> v_min_u32/v_max_u32)
#define CE_ASC(x, y)                    \
  {                                     \
    u32 _a = (x), _b = (y);             \
    (x) = min(_a, _b);                  \
    (y) = max(_a, _b);                  \
  }

// Batcher odd-even mergesort, ascending, static indices. n=16: 63 CE; n=32: 191 CE.
template <int NQ>
__device__ __forceinline__ void oems_sort(u32* s) {
#pragma unroll
  for (int p = 1; p < NQ; p <<= 1) {
#pragma unroll
    for (int k = p; k >= 1; k >>= 1) {
#pragma unroll
      for (int j = k & (p - 1); j + k < NQ; j += 2 * k) {
#pragma unroll
        for (int i = 0; i < k; ++i) {
          if ((i + j) / (2 * p) == (i + j + k) / (2 * p)) {
            CE_ASC(s[i + j], s[i + j + k])
          }
        }
      }
    }
  }
}

// merge sorted-asc batch s[16] into sorted-asc a[16] (keep 16 smallest of union)
__device__ __forceinline__ void merge_into(u32 a[KSEL], const u32 s[KSEL]) {
#pragma unroll
  for (int i = 0; i < KSEL; ++i) {
    u32 sv = s[KSEL - 1 - i];
    a[i] = min(a[i], sv);  // a becomes bitonic
  }
#pragma unroll
  for (int st = 8; st >= 1; st >>= 1) {  // bitonic clean-up -> ascending
#pragma unroll
    for (int i = 0; i < KSEL; ++i) {
      if ((i & st) == 0) {
        CE_ASC(a[i], a[i + st])
      }
    }
  }
}

__device__ __forceinline__ float key_to_dist(u32 k) {
  float v = sqrtf(__uint_as_float(k & 0xFFFFF800u));
  return fmaxf(v, 1e-6f);
}

// ---- exact single-point scan (fallback paths only) ----
__device__ __forceinline__ void select_scalar(float px, float py, float pz,
                                              const float* __restrict__ nodes,
                                              u32 a[KSEL], int jbase,
                                              int nbatch) {
#pragma unroll
  for (int t = 0; t < KSEL; ++t) a[t] = 0xFFFFFFFFu;
#pragma unroll 1
  for (int b = 0; b < nbatch; ++b) {
    int j0 = jbase + BATCH * b;
    const float* np = nodes + 3 * j0;
    u32 s[BATCH];
#pragma unroll
    for (int u = 0; u < BATCH; ++u) {
      float nx = np[3 * u + 0], ny = np[3 * u + 1], nz = np[3 * u + 2];
      float dx = px - nx, dy = py - ny, dz = pz - nz;
      float d2 = fmaf(dx, dx, fmaf(dy, dy, dz * dz));
      s[u] = (__float_as_uint(d2) & 0xFFFFF800u) | (u32)(j0 + u);
    }
    oems_sort<BATCH>(s);
    merge_into(a, s);
  }
}

// ---- kernel 0: pack nodes as (x,y,z,|n|^2) ----
__global__ __launch_bounds__(256) void k_pack(const float* __restrict__ nodes,
                                              float4* __restrict__ packed) {
  int i = blockIdx.x * blockDim.x + threadIdx.x;
  if (i < M_NODES) {
    float x = nodes[3 * i + 0], y = nodes[3 * i + 1], z = nodes[3 * i + 2];
    packed[i] = make_float4(x, y, z, fmaf(x, x, fmaf(y, y, z * z)));
  }
}

// ---- shared scan body (r10 structure, verbatim): wave w scans packed nodes
// [512w, 512w+512) via wave-uniform s_load; substream top-2 -> OEMS-32.
__device__ __forceinline__ void scan_slice(float px, float py, float pz,
                                           const float4* __restrict__ packed,
                                           int jbase, u32 a[KSEL]) {
  float m2x = -2.0f * px, m2y = -2.0f * py, m2z = -2.0f * pz;
  float pp = fmaf(px, px, fmaf(py, py, pz * pz));
  const u32 HMASK = 0xFFFFF800u;

  u32 t0[BATCH], t1[BATCH];
#pragma unroll
  for (int u = 0; u < BATCH; ++u) { t0[u] = 0xFFFFFFFFu; t1[u] = 0xFFFFFFFFu; }

#pragma unroll 1
  for (int b = 0; b < 512 / BATCH; ++b) {
    int j0 = jbase + BATCH * b;
    const float4* np = packed + j0;  // wave-uniform -> s_load streams
#pragma unroll
    for (int u = 0; u < BATCH; ++u) {
      float4 nd = np[u];  // (x,y,z,|n|^2) in SGPRs
      float d2 = fmaf(nd.x, m2x, fmaf(nd.y, m2y, fmaf(nd.z, m2z, nd.w + pp)));
      d2 = fmaxf(d2, 0.0f);
      u32 key = (__float_as_uint(d2) & HMASK) | (u32)(j0 + u);
      t1[u] = min(max(t0[u], key), t1[u]);  // v_med3_u32
      t0[u] = min(t0[u], key);
    }
  }

  u32 cand[2 * BATCH];
#pragma unroll
  for (int u = 0; u < BATCH; ++u) {
    cand[2 * u + 0] = t0[u];
    cand[2 * u + 1] = t1[u];
  }
  oems_sort<2 * BATCH>(cand);
#pragma unroll
  for (int t = 0; t < KSEL; ++t) a[t] = cand[t];
}

// ---- fused kernel: select (r10) + grid.sync + finish, keys stay in regs ----
__global__ __launch_bounds__(256, 8) void k_fused(
    const float* __restrict__ means, const float4* __restrict__ packed,
    const float* __restrict__ noffs, const int* __restrict__ tptr,
    float* __restrict__ sum_ptr, float* __restrict__ out, int N) {
  __shared__ u32 lists[3][64][KSEL + 1];

  int lane = threadIdx.x & 63;
  int w = __builtin_amdgcn_readfirstlane((int)(threadIdx.x >> 6));
  int n = blockIdx.x * 64 + lane;

  float px = means[3 * n + 0];
  float py = means[3 * n + 1];
  float pz = means[3 * n + 2];

  u32 a[KSEL];
  scan_slice(px, py, pz, packed, 512 * w, a);

  if (w != 0) {
#pragma unroll
    for (int t = 0; t < KSEL; ++t) lists[w - 1][lane][t] = a[t];
  }
  __syncthreads();

  if (w == 0) {
    // merge the 3 partner lists -> global top-16 per point (in registers)
#pragma unroll 1
    for (int i = 0; i < 3; ++i) {
      u32 b2[KSEL];
#pragma unroll
      for (int t = 0; t < KSEL; ++t) b2[t] = lists[i][lane][t];
      merge_into(a, b2);
    }
    float s = 0.0f;
#pragma unroll
    for (int t = 0; t < KSEL; ++t) s += key_to_dist(a[t]);
#pragma unroll
    for (int off = 32; off > 0; off >>= 1) s += __shfl_xor(s, off);
    if (lane == 0) atomicAdd(sum_ptr, s);
  }

  cg::this_grid().sync();  // all blocks' sums visible

  if (w != 0) return;

  // finish: softmax over top-16, gather offsets from L2-resident noffs[ti]
  int ti = *tptr;
  const float* op = noffs + (size_t)ti * (3 * M_NODES);
  float scale = (*sum_ptr) * (1.0f / ((float)N * (float)KSEL)) + 1e-6f;
  float inv = 1.0f / scale;
  float vmin = key_to_dist(a[0]);  // sorted ascending -> a[0] is min

  float wsum = 0.0f, mx = 0.0f, my = 0.0f, mz = 0.0f;
#pragma unroll
  for (int t = 0; t < KSEL; ++t) {
    u32 k = a[t];
    float v = key_to_dist(k);
    float e = __expf((vmin - v) * inv);
    const float* o = op + 3 * (k & 0x7FFu);
    wsum += e;
    mx = fmaf(e, o[0], mx);
    my = fmaf(e, o[1], my);
    mz = fmaf(e, o[2], mz);
  }
  float r = 1.0f / wsum;
  out[3 * n + 0] = px + mx * r;
  out[3 * n + 1] = py + my * r;
  out[3 * n + 2] = pz + mz * r;
}

// ---- fallback two-kernel path (r10 verbatim) ----
__global__ __launch_bounds__(256, 8) void k_select(
    const float* __restrict__ means, const float4* __restrict__ packed,
    u32* __restrict__ keys_out, float* __restrict__ sum_ptr, int N) {
  __shared__ u32 lists[3][64][KSEL + 1];
  int lane = threadIdx.x & 63;
  int w = __builtin_amdgcn_readfirstlane((int)(threadIdx.x >> 6));
  int n = blockIdx.x * 64 + lane;
  float px = means[3 * n + 0], py = means[3 * n + 1], pz = means[3 * n + 2];

  u32 a[KSEL];
  scan_slice(px, py, pz, packed, 512 * w, a);

  if (w != 0) {
#pragma unroll
    for (int t = 0; t < KSEL; ++t) lists[w - 1][lane][t] = a[t];
  }
  __syncthreads();
  if (w != 0) return;
#pragma unroll 1
  for (int i = 0; i < 3; ++i) {
    u32 b2[KSEL];
#pragma unroll
    for (int t = 0; t < KSEL; ++t) b2[t] = lists[i][lane][t];
    merge_into(a, b2);
  }
  u32* kp = keys_out + (size_t)n * KSEL;
#pragma unroll
  for (int t = 0; t < KSEL; t += 4) {
    *reinterpret_cast<uint4*>(kp + t) =
        make_uint4(a[t], a[t + 1], a[t + 2], a[t + 3]);
  }
  float s = 0.0f;
#pragma unroll
  for (int t = 0; t < KSEL; ++t) s += key_to_dist(a[t]);
#pragma unroll
  for (int off = 32; off > 0; off >>= 1) s += __shfl_xor(s, off);
  if (lane == 0) atomicAdd(sum_ptr, s);
}

template <bool RELOAD>
__global__ __launch_bounds__(256) void k_finish(
    const float* __restrict__ means, const float* __restrict__ nodes,
    const float* __restrict__ noffs, const int* __restrict__ tptr,
    const u32* __restrict__ keys, const float* __restrict__ sum_ptr,
    float* __restrict__ out, int N) {
  __shared__ float4 so[M_NODES];
  int ti = *tptr;
  {
    const float* src = noffs + (size_t)ti * (3 * M_NODES);
    for (int i = threadIdx.x; i < M_NODES; i += blockDim.x) {
      so[i] = make_float4(src[3 * i + 0], src[3 * i + 1], src[3 * i + 2], 0.0f);
    }
  }
  __syncthreads();

  int n = blockIdx.x * blockDim.x + threadIdx.x;
  float px = means[3 * n + 0];
  float py = means[3 * n + 1];
  float pz = means[3 * n + 2];

  u32 a[KSEL];
  if constexpr (!RELOAD) {
    select_scalar(px, py, pz, nodes, a, 0, M_NODES / BATCH);
  } else {
    const uint4* kp = reinterpret_cast<const uint4*>(keys + (size_t)n * KSEL);
#pragma unroll
    for (int t = 0; t < 4; ++t) {
      uint4 v = kp[t];
      a[4 * t + 0] = v.x; a[4 * t + 1] = v.y;
      a[4 * t + 2] = v.z; a[4 * t + 3] = v.w;
    }
  }

  float scale = (*sum_ptr) * (1.0f / ((float)N * (float)KSEL)) + 1e-6f;
  float inv = 1.0f / scale;
  float vmin = key_to_dist(a[0]);

  float wsum = 0.0f, mx = 0.0f, my = 0.0f, mz = 0.0f;
#pragma unroll
  for (int t = 0; t < KSEL; ++t) {
    u32 k = a[t];
    float v = key_to_dist(k);
    float e = __expf((vmin - v) * inv);
    float4 o = so[k & 0x7FFu];
    wsum += e;
    mx = fmaf(e, o.x, mx);
    my = fmaf(e, o.y, my);
    mz = fmaf(e, o.z, mz);
  }
  float r = 1.0f / wsum;
  out[3 * n + 0] = px + mx * r;
  out[3 * n + 1] = py + my * r;
  out[3 * n + 2] = pz + mz * r;
}

extern "C" void kernel_launch(void* const* d_in, const int* in_sizes, int n_in,
                              void* d_out, int out_size, void* d_ws,
                              size_t ws_size, hipStream_t stream) {
  const float* means = (const float*)d_in[0];
  const float* nodes = (const float*)d_in[1];
  const float* noffs = (const float*)d_in[2];
  const int* tptr = (const int*)d_in[3];
  int N = in_sizes[0] / 3;  // 131072

  // d_ws layout: [0,256) sum | [256, 256+32K) packed nodes | keys (fallback)
  float* sum_ptr = (float*)d_ws;
  float4* packed = (float4*)((char*)d_ws + 256);
  u32* keys = (u32*)((char*)d_ws + 256 + M_NODES * sizeof(float4));
  size_t need_pack = 256 + M_NODES * sizeof(float4);
  size_t need_full = need_pack + (size_t)N * KSEL * sizeof(u32);

  size_t zbytes = ws_size < 256 ? ws_size : 256;
  if (zbytes) hipMemsetAsync(d_ws, 0, zbytes, stream);

  dim3 blk(256);
  dim3 grid_sel((unsigned)((N + 63) / 64));   // 2048 blocks = 8/CU
  dim3 grid_fin((unsigned)((N + 255) / 256));
  float* out = (float*)d_out;

  int coop = 0, dev = 0;
  hipGetDevice(&dev);
  hipDeviceGetAttribute(&coop, hipDeviceAttributeCooperativeLaunch, dev);

  if (coop && ws_size >= need_pack) {
    k_pack<<<dim3(8), blk, 0, stream>>>(nodes, packed);
    void* args[] = {(void*)&means, (void*)&packed, (void*)&noffs,
                    (void*)&tptr,  (void*)&sum_ptr, (void*)&out, (void*)&N};
    hipError_t e = hipLaunchCooperativeKernel(
        reinterpret_cast<void*>(k_fused), grid_sel, blk, args, 0, stream);
    if (e == hipSuccess) return;
    // fall through to two-kernel path on failure
  }

  if (ws_size >= need_full) {
    k_pack<<<dim3(8), blk, 0, stream>>>(nodes, packed);
    k_select<<<grid_sel, blk, 0, stream>>>(means, packed, keys, sum_ptr, N);
    k_finish<true><<<grid_fin, blk, 0, stream>>>(means, nodes, noffs, tptr,
                                                 keys, sum_ptr, out, N);
  } else {
    k_finish<false><<<grid_fin, blk, 0, stream>>>(means, nodes, noffs, tptr,
                                                  keys, sum_ptr, out, N);
  }
}

// Round 17
// 91.415 us; speedup vs baseline: 2.8450x; 2.8450x over previous
//
#include <hip/hip_runtime.h>
#include <stdint.h>

#define M_NODES 2048
#define KSEL 16
#define BATCH 16

typedef unsigned int u32;

// compare-exchange ascending (explicit min/max -> v_min_u32/v_max_u32)
#define CE_ASC(x, y)                    \
  {                                     \
    u32 _a = (x), _b = (y);             \
    (x) = min(_a, _b);                  \
    (y) = max(_a, _b);                  \
  }

// Batcher odd-even mergesort, ascending, static indices. n=16: 63 CE; n=32: 191 CE.
template <int NQ>
__device__ __forceinline__ void oems_sort(u32* s) {
#pragma unroll
  for (int p = 1; p < NQ; p <<= 1) {
#pragma unroll
    for (int k = p; k >= 1; k >>= 1) {
#pragma unroll
      for (int j = k & (p - 1); j + k < NQ; j += 2 * k) {
#pragma unroll
        for (int i = 0; i < k; ++i) {
          if ((i + j) / (2 * p) == (i + j + k) / (2 * p)) {
            CE_ASC(s[i + j], s[i + j + k])
          }
        }
      }
    }
  }
}

// merge sorted-asc batch s[16] into sorted-asc a[16] (keep 16 smallest of union)
__device__ __forceinline__ void merge_into(u32 a[KSEL], const u32 s[KSEL]) {
#pragma unroll
  for (int i = 0; i < KSEL; ++i) {
    u32 sv = s[KSEL - 1 - i];
    a[i] = min(a[i], sv);  // a becomes bitonic
  }
#pragma unroll
  for (int st = 8; st >= 1; st >>= 1) {  // bitonic clean-up -> ascending
#pragma unroll
    for (int i = 0; i < KSEL; ++i) {
      if ((i & st) == 0) {
        CE_ASC(a[i], a[i + st])
      }
    }
  }
}

__device__ __forceinline__ float key_to_dist(u32 k) {
  float v = sqrtf(__uint_as_float(k & 0xFFFFF800u));
  return fmaxf(v, 1e-6f);
}

// ---- scan body: wave scans raw nodes [jbase, jbase+512) via wave-uniform
// s_load (12B/node -> 3 aligned s_load_dwordx16 per 16-node batch, 25% fewer
// scalar bytes than the packed-float4 variant). Substream top-2 (j mod 16)
// via med3+min, then one exact OEMS-32 -> top-16.
__device__ __forceinline__ void scan_slice(float px, float py, float pz,
                                           const float* __restrict__ nodes,
                                           int jbase, u32 a[KSEL]) {
  const u32 HMASK = 0xFFFFF800u;

  u32 t0[BATCH], t1[BATCH];
#pragma unroll
  for (int u = 0; u < BATCH; ++u) { t0[u] = 0xFFFFFFFFu; t1[u] = 0xFFFFFFFFu; }

#pragma unroll 1
  for (int b = 0; b < 512 / BATCH; ++b) {
    int j0 = jbase + BATCH * b;
    const float* np = nodes + 3 * j0;  // wave-uniform -> s_load streams
#pragma unroll
    for (int u = 0; u < BATCH; ++u) {
      float nx = np[3 * u + 0];  // uniform -> SGPR
      float ny = np[3 * u + 1];
      float nz = np[3 * u + 2];
      float dx = px - nx, dy = py - ny, dz = pz - nz;
      float d2 = fmaf(dx, dx, fmaf(dy, dy, dz * dz));  // >= 0 always
      u32 key = (__float_as_uint(d2) & HMASK) | (u32)(j0 + u);
      t1[u] = min(max(t0[u], key), t1[u]);  // v_med3_u32
      t0[u] = min(t0[u], key);
    }
  }

  u32 cand[2 * BATCH];
#pragma unroll
  for (int u = 0; u < BATCH; ++u) {
    cand[2 * u + 0] = t0[u];
    cand[2 * u + 1] = t1[u];
  }
  oems_sort<2 * BATCH>(cand);
#pragma unroll
  for (int t = 0; t < KSEL; ++t) a[t] = cand[t];
}

// ---- kernel 1: block = 64 points x 4 waves; wave w scans nodes
// [512w, 512w+512); partial top-16s merged via small LDS scratch; keys
// spilled for k_finish; per-wave distance sums atomically accumulated. ----
template <bool STORE>
__global__ __launch_bounds__(256, 8) void k_select(
    const float* __restrict__ means, const float* __restrict__ nodes,
    u32* __restrict__ keys_out, float* __restrict__ sum_ptr, int N) {
  __shared__ u32 lists[3][64][KSEL + 1];

  int lane = threadIdx.x & 63;
  int w = __builtin_amdgcn_readfirstlane((int)(threadIdx.x >> 6));
  int n = blockIdx.x * 64 + lane;

  float px = means[3 * n + 0];
  float py = means[3 * n + 1];
  float pz = means[3 * n + 2];

  u32 a[KSEL];
  scan_slice(px, py, pz, nodes, 512 * w, a);

  if (w != 0) {
#pragma unroll
    for (int t = 0; t < KSEL; ++t) lists[w - 1][lane][t] = a[t];
  }
  __syncthreads();
  if (w != 0) return;  // waves 1..3 done

  // wave 0: merge the 3 partner lists -> global top-16 per point
#pragma unroll 1
  for (int i = 0; i < 3; ++i) {
    u32 b2[KSEL];
#pragma unroll
    for (int t = 0; t < KSEL; ++t) b2[t] = lists[i][lane][t];
    merge_into(a, b2);
  }

  if (STORE) {
    u32* kp = keys_out + (size_t)n * KSEL;
#pragma unroll
    for (int t = 0; t < KSEL; t += 4) {
      *reinterpret_cast<uint4*>(kp + t) =
          make_uint4(a[t], a[t + 1], a[t + 2], a[t + 3]);
    }
  }

  float s = 0.0f;
#pragma unroll
  for (int t = 0; t < KSEL; ++t) s += key_to_dist(a[t]);
#pragma unroll
  for (int off = 32; off > 0; off >>= 1) s += __shfl_xor(s, off);
  if (lane == 0) atomicAdd(sum_ptr, s);
}

// ---- kernel 2: global scale -> softmax -> gather offsets -> output ----
template <bool RELOAD>
__global__ __launch_bounds__(256) void k_finish(
    const float* __restrict__ means, const float* __restrict__ nodes,
    const float* __restrict__ noffs, const int* __restrict__ tptr,
    const u32* __restrict__ keys, const float* __restrict__ sum_ptr,
    float* __restrict__ out, int N) {
  __shared__ float4 so[M_NODES];
  int ti = *tptr;
  {
    const float* src = noffs + (size_t)ti * (3 * M_NODES);
    for (int i = threadIdx.x; i < M_NODES; i += blockDim.x) {
      so[i] = make_float4(src[3 * i + 0], src[3 * i + 1], src[3 * i + 2], 0.0f);
    }
  }
  __syncthreads();

  int n = blockIdx.x * blockDim.x + threadIdx.x;
  float px = means[3 * n + 0];
  float py = means[3 * n + 1];
  float pz = means[3 * n + 2];

  u32 a[KSEL];
  if constexpr (!RELOAD) {
    // fallback (ws too small for key spill): full rescan via scan_slice x4
    u32 tmp[KSEL];
    scan_slice(px, py, pz, nodes, 0, a);
#pragma unroll 1
    for (int c = 1; c < 4; ++c) {
      scan_slice(px, py, pz, nodes, 512 * c, tmp);
      merge_into(a, tmp);
    }
  } else {
    const uint4* kp = reinterpret_cast<const uint4*>(keys + (size_t)n * KSEL);
#pragma unroll
    for (int t = 0; t < 4; ++t) {
      uint4 v = kp[t];
      a[4 * t + 0] = v.x; a[4 * t + 1] = v.y;
      a[4 * t + 2] = v.z; a[4 * t + 3] = v.w;
    }
  }

  float scale = (*sum_ptr) * (1.0f / ((float)N * (float)KSEL)) + 1e-6f;
  float inv = 1.0f / scale;
  float vmin = key_to_dist(a[0]);  // a[] sorted ascending -> a[0] is min

  float wsum = 0.0f, mx = 0.0f, my = 0.0f, mz = 0.0f;
#pragma unroll
  for (int t = 0; t < KSEL; ++t) {
    u32 k = a[t];
    float v = key_to_dist(k);
    float e = __expf((vmin - v) * inv);  // softmax(-v/scale), max-shifted
    float4 o = so[k & 0x7FFu];
    wsum += e;
    mx = fmaf(e, o.x, mx);
    my = fmaf(e, o.y, my);
    mz = fmaf(e, o.z, mz);
  }
  float r = 1.0f / wsum;
  out[3 * n + 0] = px + mx * r;
  out[3 * n + 1] = py + my * r;
  out[3 * n + 2] = pz + mz * r;
}

extern "C" void kernel_launch(void* const* d_in, const int* in_sizes, int n_in,
                              void* d_out, int out_size, void* d_ws,
                              size_t ws_size, hipStream_t stream) {
  const float* means = (const float*)d_in[0];
  const float* nodes = (const float*)d_in[1];
  const float* noffs = (const float*)d_in[2];
  const int* tptr = (const int*)d_in[3];
  int N = in_sizes[0] / 3;  // 131072

  // d_ws layout: [0,256) sum | [256, ...) keys
  float* sum_ptr = (float*)d_ws;
  u32* keys = (u32*)((char*)d_ws + 256);
  size_t need_full = 256 + (size_t)N * KSEL * sizeof(u32);

  size_t zbytes = ws_size < 256 ? ws_size : 256;
  if (zbytes) hipMemsetAsync(d_ws, 0, zbytes, stream);

  dim3 blk(256);
  dim3 grid_sel((unsigned)((N + 63) / 64));   // 64 points per block
  dim3 grid_fin((unsigned)((N + 255) / 256));
  float* out = (float*)d_out;

  if (ws_size >= need_full) {
    k_select<true><<<grid_sel, blk, 0, stream>>>(means, nodes, keys, sum_ptr, N);
    k_finish<true><<<grid_fin, blk, 0, stream>>>(means, nodes, noffs, tptr,
                                                 keys, sum_ptr, out, N);
  } else {
    // ws too small to spill keys: recompute selection in kernel 2
    k_select<false><<<grid_sel, blk, 0, stream>>>(means, nodes, nullptr,
                                                  sum_ptr, N);
    k_finish<false><<<grid_fin, blk, 0, stream>>>(means, nodes, noffs, tptr,
                                                  keys, sum_ptr, out, N);
  }
}

// Round 18
// 84.617 us; speedup vs baseline: 3.0735x; 1.0803x over previous
//
#include <hip/hip_runtime.h>
#include <stdint.h>

#define M_NODES 2048
#define KSEL 16
#define BATCH 16

typedef unsigned int u32;

// compare-exchange ascending (explicit min/max -> v_min_u32/v_max_u32)
#define CE_ASC(x, y)                    \
  {                                     \
    u32 _a = (x), _b = (y);             \
    (x) = min(_a, _b);                  \
    (y) = max(_a, _b);                  \
  }

// Batcher odd-even mergesort, ascending, static indices. n=16: 63 CE; n=32: 191 CE.
template <int NQ>
__device__ __forceinline__ void oems_sort(u32* s) {
#pragma unroll
  for (int p = 1; p < NQ; p <<= 1) {
#pragma unroll
    for (int k = p; k >= 1; k >>= 1) {
#pragma unroll
      for (int j = k & (p - 1); j + k < NQ; j += 2 * k) {
#pragma unroll
        for (int i = 0; i < k; ++i) {
          if ((i + j) / (2 * p) == (i + j + k) / (2 * p)) {
            CE_ASC(s[i + j], s[i + j + k])
          }
        }
      }
    }
  }
}

// merge sorted-asc batch s[16] into sorted-asc a[16] (keep 16 smallest of union)
__device__ __forceinline__ void merge_into(u32 a[KSEL], const u32 s[KSEL]) {
#pragma unroll
  for (int i = 0; i < KSEL; ++i) {
    u32 sv = s[KSEL - 1 - i];
    a[i] = min(a[i], sv);  // a becomes bitonic
  }
#pragma unroll
  for (int st = 8; st >= 1; st >>= 1) {  // bitonic clean-up -> ascending
#pragma unroll
    for (int i = 0; i < KSEL; ++i) {
      if ((i & st) == 0) {
        CE_ASC(a[i], a[i + st])
      }
    }
  }
}

__device__ __forceinline__ float key_to_dist(u32 k) {
  float v = sqrtf(__uint_as_float(k & 0xFFFFF800u));
  return fmaxf(v, 1e-6f);
}

// ---- kernel 0: pack nodes as (x,y,z,|n|^2) — gives aligned float4 s_load
// streams (r17 showed raw 12B nodes regress: broken dwordx16 pattern). ----
__global__ __launch_bounds__(256) void k_pack(const float* __restrict__ nodes,
                                              float4* __restrict__ packed) {
  int i = blockIdx.x * blockDim.x + threadIdx.x;
  if (i < M_NODES) {
    float x = nodes[3 * i + 0], y = nodes[3 * i + 1], z = nodes[3 * i + 2];
    packed[i] = make_float4(x, y, z, fmaf(x, x, fmaf(y, y, z * z)));
  }
}

// ---- r10-verbatim scan body: wave scans packed nodes [jbase, jbase+512)
// via wave-uniform s_load; substream top-2 (j mod 16) -> exact OEMS-32.
__device__ __forceinline__ void scan_slice(float px, float py, float pz,
                                           const float4* __restrict__ packed,
                                           int jbase, u32 a[KSEL]) {
  float m2x = -2.0f * px, m2y = -2.0f * py, m2z = -2.0f * pz;
  float pp = fmaf(px, px, fmaf(py, py, pz * pz));
  const u32 HMASK = 0xFFFFF800u;

  u32 t0[BATCH], t1[BATCH];
#pragma unroll
  for (int u = 0; u < BATCH; ++u) { t0[u] = 0xFFFFFFFFu; t1[u] = 0xFFFFFFFFu; }

#pragma unroll 1
  for (int b = 0; b < 512 / BATCH; ++b) {
    int j0 = jbase + BATCH * b;
    const float4* np = packed + j0;  // wave-uniform -> s_load_dwordx16 x4
#pragma unroll
    for (int u = 0; u < BATCH; ++u) {
      float4 nd = np[u];  // (x,y,z,|n|^2) in SGPRs
      float d2 = fmaf(nd.x, m2x, fmaf(nd.y, m2y, fmaf(nd.z, m2z, nd.w + pp)));
      d2 = fmaxf(d2, 0.0f);  // cancellation guard
      u32 key = (__float_as_uint(d2) & HMASK) | (u32)(j0 + u);
      t1[u] = min(max(t0[u], key), t1[u]);  // v_med3_u32
      t0[u] = min(t0[u], key);
    }
  }

  u32 cand[2 * BATCH];
#pragma unroll
  for (int u = 0; u < BATCH; ++u) {
    cand[2 * u + 0] = t0[u];
    cand[2 * u + 1] = t1[u];
  }
  oems_sort<2 * BATCH>(cand);
#pragma unroll
  for (int t = 0; t < KSEL; ++t) a[t] = cand[t];
}

// ---- kernel 1 (r10 verbatim): block = 64 points x 4 waves ----
template <bool STORE>
__global__ __launch_bounds__(256, 8) void k_select(
    const float* __restrict__ means, const float4* __restrict__ packed,
    u32* __restrict__ keys_out, float* __restrict__ sum_ptr, int N) {
  __shared__ u32 lists[3][64][KSEL + 1];

  int lane = threadIdx.x & 63;
  int w = __builtin_amdgcn_readfirstlane((int)(threadIdx.x >> 6));
  int n = blockIdx.x * 64 + lane;

  float px = means[3 * n + 0];
  float py = means[3 * n + 1];
  float pz = means[3 * n + 2];

  u32 a[KSEL];
  scan_slice(px, py, pz, packed, 512 * w, a);

  if (w != 0) {
#pragma unroll
    for (int t = 0; t < KSEL; ++t) lists[w - 1][lane][t] = a[t];
  }
  __syncthreads();
  if (w != 0) return;  // waves 1..3 done

  // wave 0: merge the 3 partner lists -> global top-16 per point
#pragma unroll 1
  for (int i = 0; i < 3; ++i) {
    u32 b2[KSEL];
#pragma unroll
    for (int t = 0; t < KSEL; ++t) b2[t] = lists[i][lane][t];
    merge_into(a, b2);
  }

  if (STORE) {
    u32* kp = keys_out + (size_t)n * KSEL;
#pragma unroll
    for (int t = 0; t < KSEL; t += 4) {
      *reinterpret_cast<uint4*>(kp + t) =
          make_uint4(a[t], a[t + 1], a[t + 2], a[t + 3]);
    }
  }

  float s = 0.0f;
#pragma unroll
  for (int t = 0; t < KSEL; ++t) s += key_to_dist(a[t]);
#pragma unroll
  for (int off = 32; off > 0; off >>= 1) s += __shfl_xor(s, off);
  if (lane == 0) atomicAdd(sum_ptr, s);
}

// ---- kernel 2: softmax + DIRECT global gather (noffs[ti] is 24KB L2-hot;
// no LDS stage, no barrier, no occupancy cap) ----
__global__ __launch_bounds__(256) void k_finish(
    const float* __restrict__ means, const float* __restrict__ noffs,
    const int* __restrict__ tptr, const u32* __restrict__ keys,
    const float* __restrict__ sum_ptr, float* __restrict__ out, int N) {
  int n = blockIdx.x * blockDim.x + threadIdx.x;
  int ti = *tptr;
  const float* op = noffs + (size_t)ti * (3 * M_NODES);

  u32 a[KSEL];
  const uint4* kp = reinterpret_cast<const uint4*>(keys + (size_t)n * KSEL);
#pragma unroll
  for (int t = 0; t < 4; ++t) {
    uint4 v = kp[t];
    a[4 * t + 0] = v.x; a[4 * t + 1] = v.y;
    a[4 * t + 2] = v.z; a[4 * t + 3] = v.w;
  }

  float px = means[3 * n + 0];
  float py = means[3 * n + 1];
  float pz = means[3 * n + 2];

  float scale = (*sum_ptr) * (1.0f / ((float)N * (float)KSEL)) + 1e-6f;
  float inv = 1.0f / scale;
  float vmin = key_to_dist(a[0]);  // sorted ascending -> a[0] is min

  float wsum = 0.0f, mx = 0.0f, my = 0.0f, mz = 0.0f;
#pragma unroll
  for (int t = 0; t < KSEL; ++t) {
    u32 k = a[t];
    float v = key_to_dist(k);
    float e = __expf((vmin - v) * inv);  // softmax(-v/scale), max-shifted
    const float* o = op + 3 * (k & 0x7FFu);  // L2-hot gather
    wsum += e;
    mx = fmaf(e, o[0], mx);
    my = fmaf(e, o[1], my);
    mz = fmaf(e, o[2], mz);
  }
  float r = 1.0f / wsum;
  out[3 * n + 0] = px + mx * r;
  out[3 * n + 1] = py + my * r;
  out[3 * n + 2] = pz + mz * r;
}

// ---- fallback: no-workspace path (rescan in finish, LDS-staged gather) ----
__global__ __launch_bounds__(256, 8) void k_select_nows(
    const float* __restrict__ means, const float* __restrict__ nodes,
    float* __restrict__ sum_ptr, int N) {
  __shared__ u32 lists[3][64][KSEL + 1];
  __shared__ float4 packed_l[M_NODES];
  for (int i = threadIdx.x; i < M_NODES; i += 256) {
    float x = nodes[3 * i + 0], y = nodes[3 * i + 1], z = nodes[3 * i + 2];
    packed_l[i] = make_float4(x, y, z, fmaf(x, x, fmaf(y, y, z * z)));
  }
  __syncthreads();
  int lane = threadIdx.x & 63;
  int w = __builtin_amdgcn_readfirstlane((int)(threadIdx.x >> 6));
  int n = blockIdx.x * 64 + lane;
  float px = means[3 * n + 0], py = means[3 * n + 1], pz = means[3 * n + 2];
  u32 a[KSEL];
  scan_slice(px, py, pz, packed_l, 512 * w, a);
  if (w != 0) {
#pragma unroll
    for (int t = 0; t < KSEL; ++t) lists[w - 1][lane][t] = a[t];
  }
  __syncthreads();
  if (w != 0) return;
#pragma unroll 1
  for (int i = 0; i < 3; ++i) {
    u32 b2[KSEL];
#pragma unroll
    for (int t = 0; t < KSEL; ++t) b2[t] = lists[i][lane][t];
    merge_into(a, b2);
  }
  float s = 0.0f;
#pragma unroll
  for (int t = 0; t < KSEL; ++t) s += key_to_dist(a[t]);
#pragma unroll
  for (int off = 32; off > 0; off >>= 1) s += __shfl_xor(s, off);
  if (lane == 0) atomicAdd(sum_ptr, s);
}

__global__ __launch_bounds__(256) void k_finish_nows(
    const float* __restrict__ means, const float* __restrict__ nodes,
    const float* __restrict__ noffs, const int* __restrict__ tptr,
    const float* __restrict__ sum_ptr, float* __restrict__ out, int N) {
  __shared__ float4 packed_l[M_NODES];
  for (int i = threadIdx.x; i < M_NODES; i += 256) {
    float x = nodes[3 * i + 0], y = nodes[3 * i + 1], z = nodes[3 * i + 2];
    packed_l[i] = make_float4(x, y, z, fmaf(x, x, fmaf(y, y, z * z)));
  }
  __syncthreads();
  int n = blockIdx.x * blockDim.x + threadIdx.x;
  int ti = *tptr;
  const float* op = noffs + (size_t)ti * (3 * M_NODES);
  float px = means[3 * n + 0], py = means[3 * n + 1], pz = means[3 * n + 2];
  u32 a[KSEL], tmp[KSEL];
  scan_slice(px, py, pz, packed_l, 0, a);
#pragma unroll 1
  for (int c = 1; c < 4; ++c) {
    scan_slice(px, py, pz, packed_l, 512 * c, tmp);
    merge_into(a, tmp);
  }
  float scale = (*sum_ptr) * (1.0f / ((float)N * (float)KSEL)) + 1e-6f;
  float inv = 1.0f / scale;
  float vmin = key_to_dist(a[0]);
  float wsum = 0.0f, mx = 0.0f, my = 0.0f, mz = 0.0f;
#pragma unroll
  for (int t = 0; t < KSEL; ++t) {
    u32 k = a[t];
    float v = key_to_dist(k);
    float e = __expf((vmin - v) * inv);
    const float* o = op + 3 * (k & 0x7FFu);
    wsum += e;
    mx = fmaf(e, o[0], mx);
    my = fmaf(e, o[1], my);
    mz = fmaf(e, o[2], mz);
  }
  float r = 1.0f / wsum;
  out[3 * n + 0] = px + mx * r;
  out[3 * n + 1] = py + my * r;
  out[3 * n + 2] = pz + mz * r;
}

extern "C" void kernel_launch(void* const* d_in, const int* in_sizes, int n_in,
                              void* d_out, int out_size, void* d_ws,
                              size_t ws_size, hipStream_t stream) {
  const float* means = (const float*)d_in[0];
  const float* nodes = (const float*)d_in[1];
  const float* noffs = (const float*)d_in[2];
  const int* tptr = (const int*)d_in[3];
  int N = in_sizes[0] / 3;  // 131072

  // d_ws layout: [0,256) sum | [256, 256+32K) packed nodes | keys
  float* sum_ptr = (float*)d_ws;
  float4* packed = (float4*)((char*)d_ws + 256);
  u32* keys = (u32*)((char*)d_ws + 256 + M_NODES * sizeof(float4));
  size_t need_full =
      256 + M_NODES * sizeof(float4) + (size_t)N * KSEL * sizeof(u32);

  size_t zbytes = ws_size < 256 ? ws_size : 256;
  if (zbytes) hipMemsetAsync(d_ws, 0, zbytes, stream);

  dim3 blk(256);
  dim3 grid_sel((unsigned)((N + 63) / 64));   // 64 points per block
  dim3 grid_fin((unsigned)((N + 255) / 256));
  float* out = (float*)d_out;

  if (ws_size >= need_full) {
    k_pack<<<dim3(8), blk, 0, stream>>>(nodes, packed);
    k_select<true><<<grid_sel, blk, 0, stream>>>(means, packed, keys, sum_ptr, N);
    k_finish<<<grid_fin, blk, 0, stream>>>(means, noffs, tptr, keys, sum_ptr,
                                           out, N);
  } else {
    k_select_nows<<<grid_sel, blk, 0, stream>>>(means, nodes, sum_ptr, N);
    k_finish_nows<<<grid_fin, blk, 0, stream>>>(means, nodes, noffs, tptr,
                                                sum_ptr, out, N);
  }
}